// Round 5
// baseline (443.895 us; speedup 1.0000x reference)
//
#include <hip/hip_runtime.h>
#include <hip/hip_bf16.h>

#define BT 16384   // B*T = 32*512
#define DIM 768
#define NH 12
#define DFF 3072

typedef __attribute__((ext_vector_type(8))) short short8;
typedef __attribute__((ext_vector_type(4))) float floatx4;
typedef __attribute__((ext_vector_type(4))) unsigned short ushort4b;

using bf16 = __hip_bfloat16;

static __device__ __forceinline__ float b2f(bf16 v) { return __bfloat162float(v); }
static __device__ __forceinline__ bf16 f2b(float v) { return __float2bfloat16(v); }

// async global->LDS DMA, 16B per lane; LDS dest is wave-uniform base (HW adds lane*16)
static __device__ __forceinline__ void gload_lds16(const void* g, void* l) {
    __builtin_amdgcn_global_load_lds(
        (const __attribute__((address_space(1))) unsigned int*)g,
        (__attribute__((address_space(3))) unsigned int*)l, 16, 0, 0);
}

// ---- small pack: wqkv [256][768] (rows>=216 zero), wo_t [768][96] (k>=72 zero) ----
__global__ __launch_bounds__(256) void pack_small_kernel(
    const float* __restrict__ Wq, const float* __restrict__ Wk, const float* __restrict__ Wv,
    const float* __restrict__ Wo, bf16* __restrict__ wqkv, bf16* __restrict__ wo_t)
{
    int i = blockIdx.x * 256 + threadIdx.x;
    const int S0 = 256 * 768, S1 = 768 * 96;
    if (i < S0) {
        int c = i / 768, dd = i % 768;
        float v = 0.f;
        if (c < 216) {
            int sel = c / 72, cc = c % 72, h = cc / 6, e = cc % 6;
            const float* W = (sel == 0) ? Wq : (sel == 1) ? Wk : Wv;   // (H, D, E)
            v = W[((size_t)h * 768 + dd) * 6 + e];
        }
        wqkv[i] = f2b(v);
    } else if ((i -= S0) < S1) {
        int n = i / 96, r = i % 96;              // Wo is (72, 768): [r][n]
        wo_t[i] = f2b(r < 72 ? Wo[r * 768 + n] : 0.f);
    }
}

// ---- tiled transpose: in fp32 [R][C] -> out bf16 [C][R]; grid (C/32, R/32), 256 thr ----
__global__ __launch_bounds__(256) void transpose_kernel(
    const float* __restrict__ in, bf16* __restrict__ out, int R, int C)
{
    __shared__ float t[32][33];
    int c0 = blockIdx.x * 32, r0 = blockIdx.y * 32;
    int cx = threadIdx.x & 31, ry = threadIdx.x >> 5;   // ry 0..7
#pragma unroll
    for (int j = 0; j < 4; j++)
        t[ry + j * 8][cx] = in[(size_t)(r0 + ry + j * 8) * C + c0 + cx];
    __syncthreads();
    int rx = cx, cy = ry;
#pragma unroll
    for (int j = 0; j < 4; j++)
        out[(size_t)(c0 + cy + j * 8) * R + r0 + rx] = f2b(t[rx][cy + j * 8]);
}

// ---------------- LayerNorm: 192 threads, float4 loads, 8B packed bf16 stores ----------------
__global__ __launch_bounds__(192) void ln_kernel(
    const float* __restrict__ x, const float* __restrict__ g, const float* __restrict__ be,
    bf16* __restrict__ out)
{
    int row = blockIdx.x;
    int tid = threadIdx.x;
    const float4* xr = (const float4*)(x + (size_t)row * DIM);
    float4 v = xr[tid];
    float s = v.x + v.y + v.z + v.w;
    float s2 = v.x * v.x + v.y * v.y + v.z * v.z + v.w * v.w;
#pragma unroll
    for (int off = 32; off; off >>= 1) {
        s += __shfl_down(s, off);
        s2 += __shfl_down(s2, off);
    }
    __shared__ float red[6];
    int wv = tid >> 6, ln = tid & 63;
    if (ln == 0) { red[wv] = s; red[3 + wv] = s2; }
    __syncthreads();
    float ts = red[0] + red[1] + red[2];
    float ts2 = red[3] + red[4] + red[5];
    float mean = ts * (1.f / 768.f);
    float var = ts2 * (1.f / 768.f) - mean * mean;
    float rstd = rsqrtf(var + 1e-5f);
    int c = tid * 4;
    float o0 = (v.x - mean) * rstd * g[c + 0] + be[c + 0];
    float o1 = (v.y - mean) * rstd * g[c + 1] + be[c + 1];
    float o2 = (v.z - mean) * rstd * g[c + 2] + be[c + 2];
    float o3 = (v.w - mean) * rstd * g[c + 3] + be[c + 3];
    bf16 h0 = f2b(o0), h1 = f2b(o1), h2 = f2b(o2), h3 = f2b(o3);
    ushort4b pk;
    pk[0] = *(unsigned short*)&h0; pk[1] = *(unsigned short*)&h1;
    pk[2] = *(unsigned short*)&h2; pk[3] = *(unsigned short*)&h3;
    *(ushort4b*)(out + (size_t)row * DIM + c) = pk;
}

// ---------------- MFMA bf16 GEMM (128x128, m97-structure) for small-N / small-K GEMMs ----------
template <int NSLAB, bool RELU, bool BIAS, bool RES, bool BF16OUT>
__global__ __launch_bounds__(256) void gemm_kernel(
    const bf16* __restrict__ A, const bf16* __restrict__ Bt,
    const float* __restrict__ bias, const float* __restrict__ res,
    void* __restrict__ Cv, int M, int N, int K)
{
    constexpr int SMEM_BYTES = BF16OUT ? (128 * 136 * 2) : (NSLAB * 2 * 128 * 32 * 2);
    __shared__ __align__(16) char smem[SMEM_BYTES];
    bf16* lA = (bf16*)smem;                       // [NSLAB][128][32]
    bf16* lB = lA + NSLAB * 128 * 32;

    const int tid = threadIdx.x;
    const int bm = blockIdx.x * 128;
    const int bn = blockIdx.y * 128;
    const int wave = tid >> 6, lane = tid & 63;
    const int wm = (wave >> 1) * 64, wn = (wave & 1) * 64;
    const int quad = lane >> 4, l16 = lane & 15;
    const int lrow = lane >> 2;          // 0..15: row within 16-row DMA slab
    const int lkc = (lane & 3) * 8;      // 0,8,16,24: k offset within slab

    floatx4 acc[4][4] = {};

    for (int k0 = 0; k0 < K; k0 += NSLAB * 32) {
#pragma unroll
        for (int s = 0; s < NSLAB; s++) {
#pragma unroll
            for (int it = 0; it < 2; it++) {
                int r = wave * 32 + it * 16;
                gload_lds16(A + (size_t)(bm + r + lrow) * K + k0 + s * 32 + lkc,
                            lA + s * 4096 + r * 32);
                gload_lds16(Bt + (size_t)(bn + r + lrow) * K + k0 + s * 32 + lkc,
                            lB + s * 4096 + r * 32);
            }
        }
        __syncthreads();
#pragma unroll
        for (int s = 0; s < NSLAB; s++) {
            short8 af[4], bfr[4];
#pragma unroll
            for (int mt = 0; mt < 4; mt++)
                af[mt] = *(const short8*)(lA + s * 4096 + (wm + mt * 16 + l16) * 32 + quad * 8);
#pragma unroll
            for (int nt = 0; nt < 4; nt++)
                bfr[nt] = *(const short8*)(lB + s * 4096 + (wn + nt * 16 + l16) * 32 + quad * 8);
#pragma unroll
            for (int mt = 0; mt < 4; mt++)
#pragma unroll
                for (int nt = 0; nt < 4; nt++)
                    acc[mt][nt] = __builtin_amdgcn_mfma_f32_16x16x32_bf16(af[mt], bfr[nt], acc[mt][nt], 0, 0, 0);
        }
        __syncthreads();
    }

    if constexpr (BF16OUT) {
        bf16* ltile = (bf16*)smem;   // safe: loop ended with __syncthreads()
#pragma unroll
        for (int mt = 0; mt < 4; mt++) {
#pragma unroll
            for (int nt = 0; nt < 4; nt++) {
                int tc = wn + nt * 16 + l16;
#pragma unroll
                for (int r = 0; r < 4; r++) {
                    int tr = wm + mt * 16 + quad * 4 + r;
                    float v0 = acc[mt][nt][r];
                    if constexpr (BIAS) v0 += bias[bn + tc];
                    if constexpr (RELU) v0 = fmaxf(v0, 0.f);
                    ltile[tr * 136 + tc] = f2b(v0);
                }
            }
        }
        __syncthreads();
        bf16* C = (bf16*)Cv;
        int rr0 = tid >> 4, col8 = (tid & 15) * 8;
        int gc = bn + col8;
#pragma unroll
        for (int p = 0; p < 8; p++) {
            int rr = p * 16 + rr0;
            if (gc < N)
                *(short8*)(C + (size_t)(bm + rr) * N + gc) =
                    *(const short8*)(ltile + rr * 136 + col8);
        }
    } else {
        float* C = (float*)Cv;
#pragma unroll
        for (int mt = 0; mt < 4; mt++) {
#pragma unroll
            for (int nt = 0; nt < 4; nt++) {
                int gc = bn + wn + nt * 16 + l16;
                if (gc < N) {
#pragma unroll
                    for (int r = 0; r < 4; r++) {
                        int gr = bm + wm + mt * 16 + quad * 4 + r;
                        float v0 = acc[mt][nt][r];
                        if constexpr (BIAS) v0 += bias[gc];
                        if constexpr (RES) v0 += res[(size_t)gr * N + gc];
                        if constexpr (RELU) v0 = fmaxf(v0, 0.f);
                        C[(size_t)gr * N + gc] = v0;
                    }
                }
            }
        }
    }
}

// ============== 256x192 4-phase GEMM, persistent, LDS-read-BALANCED phases ====================
// BM=256, BN=192, BK=64, 512 threads = 8 waves (4M x 2N), per-wave 64x96 (4x6 16x16 frags).
// Grid fixed at 256 blocks; block owns bm = sid%64 and TPB bn-tiles. K = NTC*64 compile-time.
// LDS-read balance is the point (r4 post-mortem): 160 ds_read_b128/CU/group must spread evenly
// or the tail burst stalls ph0 (lgkmcnt completes in-order). Per-phase reads/wave: 4/6/6/4.
//   ph0: LDA(1,cb)[4];            MM(0,0); BAR
//   ph1: LDB(1,cb)[6];            MM(1,0); VMW(0) [tile G+1 chunks, issued >=4 phases ago]; BAR
//   ph2: stage A(G+2)[4 DMA]; LDB(0,nb)[6]; MM(1,1); BAR      <- b0(G+1) lands under ph2+ph3
//   ph3: stage B(G+2)[3 DMA]; MM(0,1); LDA(0,nb)[4]; BAR      <- a0 reload after its last use
// Race discipline: every LDS region's reads are >=2 barriers before that region's re-stage;
// nb reads occur only after VMW(0)+BAR published tile G+1.
// BF16OUT epilogue at tile end via free 28KB LDS scratch (pipeline stays live).
template <int NTC, int TPB, bool RELU, bool BIAS, bool RES, bool BF16OUT>
__global__ __launch_bounds__(512, 2) void gemm192_kernel(
    const bf16* __restrict__ A, const bf16* __restrict__ Bt,
    const float* __restrict__ bias, const float* __restrict__ res,
    void* __restrict__ Cv, int N)
{
    constexpr int KC = NTC * 64;
    constexpr int NG = NTC * TPB;
    extern __shared__ __align__(16) char smem[];

    const int sid = ((blockIdx.x & 7) << 5) + (blockIdx.x >> 3);   // XCD swizzle, grid=256
    const int bm = (sid & 63) << 8;
    const int bnBase = (sid >> 6) * (TPB * 192);

    const int tid = threadIdx.x;
    const int w = tid >> 6, lane = tid & 63;
    const int wm = w >> 1, wn = w & 1;              // 4 x 2 wave grid
    const int l16 = lane & 15, quad = lane >> 4;

    // staging: chunk = 64 rows x 64 cols bf16 = 8KB, one gload_lds16 per thread.
    const int rstg = (w >> 1) * 16 + (lane >> 2);
    const int cstg = (w & 1) * 32 + (((lane & 3) * 8) ^ ((lane & 32) ? 16 : 0));
    const bf16* aSrc = A + (size_t)(bm + rstg) * KC + cstg;
    const bf16* bSrc = Bt + (size_t)(bnBase + rstg) * KC + cstg;
    const int stgoff = w * 1024;                    // wave-uniform; HW adds lane*16

    // swizzled ds_read: logical (row R, kslab s, quad) -> byte
    //   (R>>4)*2048 + s*1024 + (R&15)*64 + (quad*16 ^ ((R&8)?32:0))
    const int xr = (quad * 16) ^ ((l16 & 8) ? 32 : 0);
    const int aoff = wm * 8192 + l16 * 64 + xr;             // + qm*4096 + fm*2048 + s*1024
    const int boff = 32768 + wn * 12288 + l16 * 64 + xr;    // + qn*6144 + fn*2048 + s*1024

#define STG2(BO, ISB, CH) gload_lds16( \
        ((ISB) ? bS2 : aS2) + (size_t)(CH) * 64 * KC, \
        smem + (BO) + (ISB) * 32768 + (CH) * 8192 + stgoff)

#define BARX() asm volatile("s_barrier" ::: "memory")
#define VMW(N_) asm volatile("s_waitcnt vmcnt(" #N_ ")" ::: "memory")
#define LGW0() asm volatile("s_waitcnt lgkmcnt(0)" ::: "memory")

    floatx4 acc[4][6] = {};
    short8 a[2][2][2], b[2][3][2];                  // a[qm][fm][s], b[qn][fn][s]

#define LDA(QM, CB) { _Pragma("unroll") for (int fm = 0; fm < 2; fm++) { \
    _Pragma("unroll") for (int s = 0; s < 2; s++) \
        a[QM][fm][s] = *(const short8*)((CB) + aoff + (QM) * 4096 + fm * 2048 + s * 1024); } }
#define LDB(QN, CB) { _Pragma("unroll") for (int fn = 0; fn < 3; fn++) { \
    _Pragma("unroll") for (int s = 0; s < 2; s++) \
        b[QN][fn][s] = *(const short8*)((CB) + boff + (QN) * 6144 + fn * 2048 + s * 1024); } }
#define MM(QM, QN) { __builtin_amdgcn_s_setprio(1); \
    _Pragma("unroll") for (int fm = 0; fm < 2; fm++) { \
    _Pragma("unroll") for (int fn = 0; fn < 3; fn++) { \
    _Pragma("unroll") for (int s = 0; s < 2; s++) \
        acc[(QM)*2+fm][(QN)*3+fn] = __builtin_amdgcn_mfma_f32_16x16x32_bf16( \
            a[QM][fm][s], b[(QN)][fn][s], acc[(QM)*2+fm][(QN)*3+fn], 0, 0, 0); } } \
    __builtin_amdgcn_s_setprio(0); }

    // prologue: all 7 chunks of vgroup0 -> buf0, then vgroup1 -> buf1 (both t=0; NTC>=2)
    {
        const bf16* aS2 = aSrc;           const bf16* bS2 = bSrc;
#pragma unroll
        for (int c = 0; c < 4; c++) STG2(0, 0, c);
#pragma unroll
        for (int c = 0; c < 3; c++) STG2(0, 1, c);
        aS2 = aSrc + 64; bS2 = bSrc + 64;
#pragma unroll
        for (int c = 0; c < 4; c++) STG2(57344, 0, c);
#pragma unroll
        for (int c = 0; c < 3; c++) STG2(57344, 1, c);
    }
    VMW(7);            // own vgroup0 chunks landed (vgroup1's 7 stay in flight)
    BARX();            // -> ALL waves' vgroup0 chunks landed
    LDA(0, smem); LDB(0, smem);     // pre-read G=0 ph0 operands (buf0)

    for (int G = 0; G < NG; ++G) {
        const int bo = (G & 1) * 57344;
        const char* cb = smem + bo;
        const char* nb = smem + (bo ^ 57344);
        const int v = G + 2;
        const bf16* aS2 = aSrc;
        const bf16* bS2 = bSrc;
        if (v < NG) {
            const int t2 = v / NTC, g2 = v - t2 * NTC;
            aS2 = aSrc + (size_t)g2 * 64;
            bS2 = bSrc + (size_t)t2 * (192 * (size_t)KC) + (size_t)g2 * 64;
        }
        // ---- ph0: MM(0,0) on pre-read a[0],b[0]; fetch A(qm1) [4 reads] ----
        LDA(1, cb);
        MM(0, 0);
        BARX();
        // ---- ph1: MM(1,0); fetch B(qn1) [6 reads]; publish tile G+1 ----
        LDB(1, cb);
        MM(1, 0);
        VMW(0);                       // tile G+1's 7 chunks, issued in G-1 -> long landed
        BARX();
        // ---- ph2: stage A(G+2); pre-read B(qn0,G+1) from nb [6 reads]; MM(1,1) ----
        if (v < NG) { STG2(bo, 0, 0); STG2(bo, 0, 1); STG2(bo, 0, 2); STG2(bo, 0, 3); }
        if (G + 1 < NG) LDB(0, nb);
        MM(1, 1);
        BARX();
        // ---- ph3: stage B(G+2); MM(0,1); reload A(qm0,G+1) [4 reads, after last a0 use] ----
        if (v < NG) { STG2(bo, 1, 0); STG2(bo, 1, 1); STG2(bo, 1, 2); }
        MM(0, 1);
        if (G + 1 < NG) LDA(0, nb);
        BARX();

        // ---- tile-end epilogue (BF16OUT): flush acc via free LDS scratch, keep pipeline live ----
        if constexpr (BF16OUT) {
            if ((G % NTC) == NTC - 1) {
                const int t = G / NTC;
                const int bnt = bnBase + t * 192;
                bf16* sc = (bf16*)(smem + 114688);          // [256][48], stride 56 elems
                bf16* C = (bf16*)Cv;
#pragma unroll
                for (int ci = 0; ci < 4; ci++) {
                    if (wn == (ci >> 1)) {
                        const int nfh = ci & 1;
#pragma unroll
                        for (int mf = 0; mf < 4; mf++) {
#pragma unroll
                            for (int n3 = 0; n3 < 3; n3++) {
                                const int nf = nfh * 3 + n3;
                                const int row = wm * 64 + mf * 16 + quad * 4;
                                float bv = BIAS ? bias[bnt + wn * 96 + nf * 16 + l16] : 0.f;
#pragma unroll
                                for (int r = 0; r < 4; r++) {
                                    float vv = acc[mf][nf][r] + bv;
                                    if constexpr (RELU) vv = fmaxf(vv, 0.f);
                                    sc[(row + r) * 56 + n3 * 16 + l16] = f2b(vv);
                                }
                            }
                        }
                    }
                    LGW0();
                    BARX();
#pragma unroll
                    for (int it = 0; it < 3; it++) {
                        int c = it * 512 + tid;             // 1536 short8s = 256 rows x 6
                        int rr = c / 6, cc = (c - rr * 6) * 8;
                        *(short8*)(C + (size_t)(bm + rr) * N + bnt + ci * 48 + cc) =
                            *(const short8*)(sc + rr * 56 + cc);
                    }
                    BARX();
                }
#pragma unroll
                for (int mf = 0; mf < 4; mf++)
#pragma unroll
                    for (int nf = 0; nf < 6; nf++)
                        acc[mf][nf] = (floatx4){0.f, 0.f, 0.f, 0.f};
            }
        }
    }

    if constexpr (!BF16OUT) {
        float* C = (float*)Cv;
        const int bn = bnBase;                      // TPB==1 for fp32-out path
#pragma unroll
        for (int mf = 0; mf < 4; mf++) {
            const int gr = bm + wm * 64 + mf * 16 + quad * 4;
#pragma unroll
            for (int nf = 0; nf < 6; nf++) {
                const int gc = bn + wn * 96 + nf * 16 + l16;
                float bv = BIAS ? bias[gc] : 0.f;
#pragma unroll
                for (int r = 0; r < 4; r++) {
                    float v = acc[mf][nf][r] + bv;
                    if constexpr (RES) v += res[(size_t)(gr + r) * N + gc];
                    if constexpr (RELU) v = fmaxf(v, 0.f);
                    C[(size_t)(gr + r) * N + gc] = v;
                }
            }
        }
    }
#undef STG2
#undef BARX
#undef VMW
#undef LGW0
#undef LDA
#undef LDB
#undef MM
}

// ---------------- causal attention, online softmax; qkv layout [BT][216]: q|k|v each 72 cols ----------------
__global__ __launch_bounds__(256) void attn_kernel(const bf16* __restrict__ qkv, bf16* __restrict__ o_pad)
{
    int blk = blockIdx.x;
    int half = blk & 1;
    int bh = blk >> 1;
    int b = bh / NH, h = bh % NH;
    int wave = threadIdx.x >> 6, lane = threadIdx.x & 63;
    const int jmap0[4] = {0, 2, 5, 7}, jmap1[4] = {1, 3, 4, 6};
    int j = half ? jmap1[wave] : jmap0[wave];
    int t = j * 64 + lane;
    int smax = half ? 448 : 512;

    __shared__ float ks[512 * 6];
    __shared__ float vs[512 * 6];
    const bf16* base = qkv + (size_t)b * 512 * 216;
    for (int i = threadIdx.x; i < smax * 6; i += 256) {
        int s = i / 6, e = i % 6;
        ks[i] = b2f(base[s * 216 + 72 + h * 6 + e]);
        vs[i] = b2f(base[s * 216 + 144 + h * 6 + e]);
    }
    __syncthreads();

    float q0 = b2f(base[t * 216 + h * 6 + 0]);
    float q1 = b2f(base[t * 216 + h * 6 + 1]);
    float q2 = b2f(base[t * 216 + h * 6 + 2]);
    float q3 = b2f(base[t * 216 + h * 6 + 3]);
    float q4 = b2f(base[t * 216 + h * 6 + 4]);
    float q5 = b2f(base[t * 216 + h * 6 + 5]);

    const float scale = 0.4082482904638630f;  // 1/sqrt(6)
    float m = -1e30f, l = 0.f;
    float o0 = 0, o1 = 0, o2 = 0, o3 = 0, o4 = 0, o5 = 0;
    for (int s = 0; s <= t; s++) {
        const float* kk = &ks[s * 6];
        float sc = (q0 * kk[0] + q1 * kk[1] + q2 * kk[2] + q3 * kk[3] + q4 * kk[4] + q5 * kk[5]) * scale;
        float nm = fmaxf(m, sc);
        float alpha = __expf(m - nm);
        float p = __expf(sc - nm);
        l = l * alpha + p;
        const float* vv = &vs[s * 6];
        o0 = o0 * alpha + p * vv[0];
        o1 = o1 * alpha + p * vv[1];
        o2 = o2 * alpha + p * vv[2];
        o3 = o3 * alpha + p * vv[3];
        o4 = o4 * alpha + p * vv[4];
        o5 = o5 * alpha + p * vv[5];
        m = nm;
    }
    float inv = 1.f / l;
    bf16* orow = o_pad + (size_t)(b * 512 + t) * 96 + h * 6;
    orow[0] = f2b(o0 * inv);
    orow[1] = f2b(o1 * inv);
    orow[2] = f2b(o2 * inv);
    orow[3] = f2b(o3 * inv);
    orow[4] = f2b(o4 * inv);
    orow[5] = f2b(o5 * inv);
    // cols 72..95 of o_pad stay poison (finite bf16): matching wo_t k-cols are zero -> contributes 0.
}

extern "C" void kernel_launch(void* const* d_in, const int* in_sizes, int n_in,
                              void* d_out, int out_size, void* d_ws, size_t ws_size,
                              hipStream_t stream)
{
    const float* x   = (const float*)d_in[0];
    const float* Wq  = (const float*)d_in[1];
    const float* Wk  = (const float*)d_in[2];
    const float* Wv  = (const float*)d_in[3];
    const float* Wo  = (const float*)d_in[4];
    const float* bo  = (const float*)d_in[5];
    const float* W1  = (const float*)d_in[6];
    const float* b1  = (const float*)d_in[7];
    const float* W2  = (const float*)d_in[8];
    const float* b2  = (const float*)d_in[9];
    const float* g1  = (const float*)d_in[10];
    const float* be1 = (const float*)d_in[11];
    const float* g2  = (const float*)d_in[12];
    const float* be2 = (const float*)d_in[13];

    char* ws = (char*)d_ws;
    size_t off = 0;
    auto alloc = [&](size_t bytes) {
        void* p = ws + off;
        off = (off + bytes + 255) & ~(size_t)255;
        return p;
    };
    bf16*  xn    = (bf16*)alloc((size_t)BT * DIM * 2);   // LN output (reused for both LNs)
    bf16*  qkvb  = (bf16*)alloc((size_t)BT * 216 * 2);
    bf16*  o_pad = (bf16*)alloc((size_t)BT * 96 * 2);
    float* x1    = (float*)alloc((size_t)BT * DIM * 4);  // residual stream after attention, fp32
    bf16*  ffb   = (bf16*)alloc((size_t)BT * DFF * 2);
    bf16*  wqkv  = (bf16*)alloc((size_t)256 * 768 * 2);  // padded to 256 rows (zeros)
    bf16*  wo_t  = (bf16*)alloc((size_t)768 * 96 * 2);
    bf16*  w1t   = (bf16*)alloc((size_t)3072 * 768 * 2);
    bf16*  w2t   = (bf16*)alloc((size_t)768 * 3072 * 2);

    // allow >64KB dynamic LDS on the 256x192 kernels (host-side, graph-capture safe)
    hipFuncSetAttribute(reinterpret_cast<const void*>(&gemm192_kernel<12, 4, true, true, false, true>),
                        hipFuncAttributeMaxDynamicSharedMemorySize, 143360);
    hipFuncSetAttribute(reinterpret_cast<const void*>(&gemm192_kernel<48, 1, false, true, true, false>),
                        hipFuncAttributeMaxDynamicSharedMemorySize, 114688);

    const int PACK_N = 256 * 768 + 768 * 96;
    pack_small_kernel<<<(PACK_N + 255) / 256, 256, 0, stream>>>(Wq, Wk, Wv, Wo, wqkv, wo_t);
    transpose_kernel<<<dim3(3072 / 32, 768 / 32), 256, 0, stream>>>(W1, w1t, 768, 3072);
    transpose_kernel<<<dim3(768 / 32, 3072 / 32), 256, 0, stream>>>(W2, w2t, 3072, 768);

    ln_kernel<<<BT, 192, 0, stream>>>(x, g1, be1, xn);
    gemm_kernel<2, false, false, false, true><<<dim3(128, 2), 256, 0, stream>>>(
        xn, wqkv, nullptr, nullptr, qkvb, BT, 216, 768);
    attn_kernel<<<32 * NH * 2, 256, 0, stream>>>(qkvb, o_pad);
    gemm_kernel<1, false, true, true, false><<<dim3(128, 6), 256, 0, stream>>>(
        o_pad, wo_t, bo, x, x1, BT, 768, 96);
    ln_kernel<<<BT, 192, 0, stream>>>(x1, g2, be2, xn);
    // FF1: [16384x768] @ [768x3072] -> bf16 (+bias, relu): persistent, grid 256, 4 bn-tiles/block
    gemm192_kernel<12, 4, true, true, false, true><<<256, 512, 143360, stream>>>(
        xn, w1t, b1, nullptr, ffb, 3072);
    // FF2: [16384x3072] @ [3072x768] -> fp32 (+bias, +res): grid 256, single tile/block
    gemm192_kernel<48, 1, false, true, true, false><<<256, 512, 114688, stream>>>(
        ffb, w2t, b2, x1, (float*)d_out, 768);
}

// Round 6
// 414.802 us; speedup vs baseline: 1.0701x; 1.0701x over previous
//
#include <hip/hip_runtime.h>
#include <hip/hip_bf16.h>

#define BT 16384   // B*T = 32*512
#define DIM 768
#define NH 12
#define DFF 3072

typedef __attribute__((ext_vector_type(8))) short short8;
typedef __attribute__((ext_vector_type(4))) float floatx4;
typedef __attribute__((ext_vector_type(4))) unsigned short ushort4b;

using bf16 = __hip_bfloat16;

static __device__ __forceinline__ float b2f(bf16 v) { return __bfloat162float(v); }
static __device__ __forceinline__ bf16 f2b(float v) { return __float2bfloat16(v); }

// async global->LDS DMA, 16B per lane; LDS dest is wave-uniform base (HW adds lane*16)
static __device__ __forceinline__ void gload_lds16(const void* g, void* l) {
    __builtin_amdgcn_global_load_lds(
        (const __attribute__((address_space(1))) unsigned int*)g,
        (__attribute__((address_space(3))) unsigned int*)l, 16, 0, 0);
}

// ---- small pack: wqkv [256][768] (rows>=216 zero), wo_t [768][96] (k>=72 zero) ----
__global__ __launch_bounds__(256) void pack_small_kernel(
    const float* __restrict__ Wq, const float* __restrict__ Wk, const float* __restrict__ Wv,
    const float* __restrict__ Wo, bf16* __restrict__ wqkv, bf16* __restrict__ wo_t)
{
    int i = blockIdx.x * 256 + threadIdx.x;
    const int S0 = 256 * 768, S1 = 768 * 96;
    if (i < S0) {
        int c = i / 768, dd = i % 768;
        float v = 0.f;
        if (c < 216) {
            int sel = c / 72, cc = c % 72, h = cc / 6, e = cc % 6;
            const float* W = (sel == 0) ? Wq : (sel == 1) ? Wk : Wv;   // (H, D, E)
            v = W[((size_t)h * 768 + dd) * 6 + e];
        }
        wqkv[i] = f2b(v);
    } else if ((i -= S0) < S1) {
        int n = i / 96, r = i % 96;              // Wo is (72, 768): [r][n]
        wo_t[i] = f2b(r < 72 ? Wo[r * 768 + n] : 0.f);
    }
}

// ---- tiled transpose: in fp32 [R][C] -> out bf16 [C][R]; grid (C/32, R/32), 256 thr ----
__global__ __launch_bounds__(256) void transpose_kernel(
    const float* __restrict__ in, bf16* __restrict__ out, int R, int C)
{
    __shared__ float t[32][33];
    int c0 = blockIdx.x * 32, r0 = blockIdx.y * 32;
    int cx = threadIdx.x & 31, ry = threadIdx.x >> 5;   // ry 0..7
#pragma unroll
    for (int j = 0; j < 4; j++)
        t[ry + j * 8][cx] = in[(size_t)(r0 + ry + j * 8) * C + c0 + cx];
    __syncthreads();
    int rx = cx, cy = ry;
#pragma unroll
    for (int j = 0; j < 4; j++)
        out[(size_t)(c0 + cy + j * 8) * R + r0 + rx] = f2b(t[rx][cy + j * 8]);
}

// ---------------- LayerNorm: 192 threads, float4 loads, 8B packed bf16 stores ----------------
__global__ __launch_bounds__(192) void ln_kernel(
    const float* __restrict__ x, const float* __restrict__ g, const float* __restrict__ be,
    bf16* __restrict__ out)
{
    int row = blockIdx.x;
    int tid = threadIdx.x;
    const float4* xr = (const float4*)(x + (size_t)row * DIM);
    float4 v = xr[tid];
    float s = v.x + v.y + v.z + v.w;
    float s2 = v.x * v.x + v.y * v.y + v.z * v.z + v.w * v.w;
#pragma unroll
    for (int off = 32; off; off >>= 1) {
        s += __shfl_down(s, off);
        s2 += __shfl_down(s2, off);
    }
    __shared__ float red[6];
    int wv = tid >> 6, ln = tid & 63;
    if (ln == 0) { red[wv] = s; red[3 + wv] = s2; }
    __syncthreads();
    float ts = red[0] + red[1] + red[2];
    float ts2 = red[3] + red[4] + red[5];
    float mean = ts * (1.f / 768.f);
    float var = ts2 * (1.f / 768.f) - mean * mean;
    float rstd = rsqrtf(var + 1e-5f);
    int c = tid * 4;
    float o0 = (v.x - mean) * rstd * g[c + 0] + be[c + 0];
    float o1 = (v.y - mean) * rstd * g[c + 1] + be[c + 1];
    float o2 = (v.z - mean) * rstd * g[c + 2] + be[c + 2];
    float o3 = (v.w - mean) * rstd * g[c + 3] + be[c + 3];
    bf16 h0 = f2b(o0), h1 = f2b(o1), h2 = f2b(o2), h3 = f2b(o3);
    ushort4b pk;
    pk[0] = *(unsigned short*)&h0; pk[1] = *(unsigned short*)&h1;
    pk[2] = *(unsigned short*)&h2; pk[3] = *(unsigned short*)&h3;
    *(ushort4b*)(out + (size_t)row * DIM + c) = pk;
}

// ---------------- MFMA bf16 GEMM (128x128, m97-structure) for small-N / small-K GEMMs ----------
template <int NSLAB, bool RELU, bool BIAS, bool RES, bool BF16OUT>
__global__ __launch_bounds__(256) void gemm_kernel(
    const bf16* __restrict__ A, const bf16* __restrict__ Bt,
    const float* __restrict__ bias, const float* __restrict__ res,
    void* __restrict__ Cv, int M, int N, int K)
{
    constexpr int SMEM_BYTES = BF16OUT ? (128 * 136 * 2) : (NSLAB * 2 * 128 * 32 * 2);
    __shared__ __align__(16) char smem[SMEM_BYTES];
    bf16* lA = (bf16*)smem;                       // [NSLAB][128][32]
    bf16* lB = lA + NSLAB * 128 * 32;

    const int tid = threadIdx.x;
    const int bm = blockIdx.x * 128;
    const int bn = blockIdx.y * 128;
    const int wave = tid >> 6, lane = tid & 63;
    const int wm = (wave >> 1) * 64, wn = (wave & 1) * 64;
    const int quad = lane >> 4, l16 = lane & 15;
    const int lrow = lane >> 2;          // 0..15: row within 16-row DMA slab
    const int lkc = (lane & 3) * 8;      // 0,8,16,24: k offset within slab

    floatx4 acc[4][4] = {};

    for (int k0 = 0; k0 < K; k0 += NSLAB * 32) {
#pragma unroll
        for (int s = 0; s < NSLAB; s++) {
#pragma unroll
            for (int it = 0; it < 2; it++) {
                int r = wave * 32 + it * 16;
                gload_lds16(A + (size_t)(bm + r + lrow) * K + k0 + s * 32 + lkc,
                            lA + s * 4096 + r * 32);
                gload_lds16(Bt + (size_t)(bn + r + lrow) * K + k0 + s * 32 + lkc,
                            lB + s * 4096 + r * 32);
            }
        }
        __syncthreads();
#pragma unroll
        for (int s = 0; s < NSLAB; s++) {
            short8 af[4], bfr[4];
#pragma unroll
            for (int mt = 0; mt < 4; mt++)
                af[mt] = *(const short8*)(lA + s * 4096 + (wm + mt * 16 + l16) * 32 + quad * 8);
#pragma unroll
            for (int nt = 0; nt < 4; nt++)
                bfr[nt] = *(const short8*)(lB + s * 4096 + (wn + nt * 16 + l16) * 32 + quad * 8);
#pragma unroll
            for (int mt = 0; mt < 4; mt++)
#pragma unroll
                for (int nt = 0; nt < 4; nt++)
                    acc[mt][nt] = __builtin_amdgcn_mfma_f32_16x16x32_bf16(af[mt], bfr[nt], acc[mt][nt], 0, 0, 0);
        }
        __syncthreads();
    }

    if constexpr (BF16OUT) {
        bf16* ltile = (bf16*)smem;   // safe: loop ended with __syncthreads()
#pragma unroll
        for (int mt = 0; mt < 4; mt++) {
#pragma unroll
            for (int nt = 0; nt < 4; nt++) {
                int tc = wn + nt * 16 + l16;
#pragma unroll
                for (int r = 0; r < 4; r++) {
                    int tr = wm + mt * 16 + quad * 4 + r;
                    float v0 = acc[mt][nt][r];
                    if constexpr (BIAS) v0 += bias[bn + tc];
                    if constexpr (RELU) v0 = fmaxf(v0, 0.f);
                    ltile[tr * 136 + tc] = f2b(v0);
                }
            }
        }
        __syncthreads();
        bf16* C = (bf16*)Cv;
        int rr0 = tid >> 4, col8 = (tid & 15) * 8;
        int gc = bn + col8;
#pragma unroll
        for (int p = 0; p < 8; p++) {
            int rr = p * 16 + rr0;
            if (gc < N)
                *(short8*)(C + (size_t)(bm + rr) * N + gc) =
                    *(const short8*)(ltile + rr * 136 + col8);
        }
    } else {
        float* C = (float*)Cv;
#pragma unroll
        for (int mt = 0; mt < 4; mt++) {
#pragma unroll
            for (int nt = 0; nt < 4; nt++) {
                int gc = bn + wn + nt * 16 + l16;
                if (gc < N) {
#pragma unroll
                    for (int r = 0; r < 4; r++) {
                        int gr = bm + wm + mt * 16 + quad * 4 + r;
                        float v0 = acc[mt][nt][r];
                        if constexpr (BIAS) v0 += bias[gc];
                        if constexpr (RES) v0 += res[(size_t)gr * N + gc];
                        if constexpr (RELU) v0 = fmaxf(v0, 0.f);
                        C[(size_t)gr * N + gc] = v0;
                    }
                }
            }
        }
    }
}

// ============== 256x256 8-phase GEMM (FF1) — r1 structure, race-fixed staging, bm-clustered ===
// BM=BN=256, BK=64, 512 threads (8 waves, 2Mx4N), per-wave 128x64 (8x4 16x16 frags).
// LDS: 2 buffers x (A[256][64] + B[256][64]) bf16 = 128 KiB dynamic, 1 block/CU.
// st_16x32 swizzle via linear LDS dest + inverse-swizzled global source; ds_read same XOR.
// REQUIRES grid = 768 (M=16384 -> nbm=64, N=3072 -> nbn=12).
// bm-clustered XCD map: hw XCD = bid&7; XCD k serves bm in {8k..8k+7} for ALL bn -> A panels
// per XCD = 8 x 384KB = 3MB, fits the 4MB L2 -> A re-reads across the bn sweep become L2 hits.
// Race-fixed stage order (every region's reads complete >=1 barrier before its re-stage):
//   ph0: read A(qm0)+B(qn0); stage Ahi(g+1 -> other buf, reads done in g-1); MM(0,0)
//   ph1: read B(qn1);                                                        MM(0,1)
//   ph2: read A(qm1);        stage Blo(g+2; B rows 0..127 read-done ph1);    MM(1,0)
//   ph3:                     stage Bhi(g+2)+Alo(g+2; done ph1/ph2);          MM(1,1); vmcnt
// vmcnt audit (in-order): per group issues Ahi[2]@ph0, Blo[2]@ph2, Bhi+Alo[4]@ph3; at ph3 VMW
// outstanding = 6 (g+1 BloBhiAlo from g-1) + 8 (this group) = 14 -> VMW(6) drains exactly the
// 8 oldest = ALL of tile g+1. Tail: g >= NT-2 -> VMW(0).
template <bool RELU, bool BIAS, bool RES, bool BF16OUT>
__global__ __launch_bounds__(512, 2) void gemm256_kernel(
    const bf16* __restrict__ A, const bf16* __restrict__ Bt,
    const float* __restrict__ bias, const float* __restrict__ res,
    void* __restrict__ Cv, int M, int N, int K)
{
    extern __shared__ __align__(16) char smem[];
    const int NT = K >> 6;
    const int k8 = blockIdx.x & 7, q = blockIdx.x >> 3;   // grid = 768
    const int bm = (k8 * 8 + (q & 7)) << 8;               // bm panel clustered per XCD
    const int bn = (q >> 3) << 8;                         // 0..11

    const int tid = threadIdx.x;
    const int w = tid >> 6, lane = tid & 63;
    const int wm = w >> 2, wn = w & 3;              // 2 x 4 wave grid
    const int l16 = lane & 15, quad = lane >> 4;

    // staging: LDS dest linear (wave base + lane*16); global source inverse-swizzled.
    const int rstg = (w >> 1) * 16 + (lane >> 2);
    const int cstg = (w & 1) * 32 + ((((lane & 3) * 8)) ^ ((lane & 32) ? 16 : 0));
    const bf16* aSrc = A + (size_t)(bm + rstg) * K + cstg;
    const bf16* bSrc = Bt + (size_t)(bn + rstg) * K + cstg;
    char* dstBase = smem + w * 1024;

    // swizzled ds_read offsets: byte = (r>>4)*2048 + s*1024 + l16*64 + (quad*16 ^ ((l16&8)?32:0))
    const int xr = (quad * 16) ^ ((l16 & 8) ? 32 : 0);
    const int aOff = wm * 16384 + l16 * 64 + xr;            // + qm*8192 + fm*2048 + s*1024
    const int bOff = 32768 + wn * 8192 + l16 * 64 + xr;     // + qn*4096 + fn*2048 + s*1024

#define STAGE(P, ISB, H, T) { \
    const bf16* _s = ((ISB) ? bSrc : aSrc) + ((size_t)((H) * 128) * K + (size_t)(T) * 64); \
    char* _d = dstBase + (P) * 65536 + (ISB) * 32768 + (H) * 16384; \
    gload_lds16(_s, _d); \
    gload_lds16(_s + (size_t)64 * K, _d + 8192); }

#define BARX() asm volatile("s_barrier" ::: "memory")
#define VMW(N_) asm volatile("s_waitcnt vmcnt(" #N_ ")" ::: "memory")

    floatx4 acc[8][4] = {};
    short8 a[4][2], b[2][2][2];

#define LDA(QM, CB) { _Pragma("unroll") for (int fm = 0; fm < 4; fm++) { \
    _Pragma("unroll") for (int s = 0; s < 2; s++) \
        a[fm][s] = *(const short8*)((CB) + aOff + (QM) * 8192 + fm * 2048 + s * 1024); } }
#define LDB(QN, CB) { _Pragma("unroll") for (int fn = 0; fn < 2; fn++) { \
    _Pragma("unroll") for (int s = 0; s < 2; s++) \
        b[QN][fn][s] = *(const short8*)((CB) + bOff + (QN) * 4096 + fn * 2048 + s * 1024); } }
#define MM(QM, QN) { __builtin_amdgcn_s_setprio(1); \
    _Pragma("unroll") for (int fm = 0; fm < 4; fm++) { \
    _Pragma("unroll") for (int fn = 0; fn < 2; fn++) { \
    _Pragma("unroll") for (int s = 0; s < 2; s++) \
        acc[(QM)*4+fm][(QN)*2+fn] = __builtin_amdgcn_mfma_f32_16x16x32_bf16( \
            a[fm][s], b[QN][fn][s], acc[(QM)*4+fm][(QN)*2+fn], 0, 0, 0); } } \
    __builtin_amdgcn_s_setprio(0); }

    // prologue: tile0 {Blo,Bhi,Alo,Ahi} -> buf0; tile1 {Blo,Bhi,Alo} -> buf1  (14 loads)
    STAGE(0, 1, 0, 0); STAGE(0, 1, 1, 0); STAGE(0, 0, 0, 0); STAGE(0, 0, 1, 0);
    STAGE(1, 1, 0, 1); STAGE(1, 1, 1, 1); STAGE(1, 0, 0, 1);
    VMW(6);            // oldest 8 loads (= all of tile0) landed
    BARX();

    for (int g = 0; g < NT; ++g) {
        const int p = g & 1, pn = p ^ 1;
        const char* cb = smem + p * 65536;
        // ---- phase 0: q=(0,0); stage Ahi(g+1) into other buffer (its reads ended in g-1) ----
        LDA(0, cb); LDB(0, cb);
        if (g + 1 < NT) STAGE(pn, 0, 1, g + 1);
        BARX(); MM(0, 0); BARX();
        // ---- phase 1: q=(0,1) ----
        LDB(1, cb);
        BARX(); MM(0, 1); BARX();
        // ---- phase 2: q=(1,0); stage Blo(g+2) (B rows 0..127 read-complete after ph1) ----
        LDA(1, cb);
        if (g + 2 < NT) STAGE(p, 1, 0, g + 2);
        BARX(); MM(1, 0); BARX();
        // ---- phase 3: q=(1,1); stage Bhi(g+2)+Alo(g+2) (read-complete after ph1/ph2) ----
        if (g + 2 < NT) { STAGE(p, 1, 1, g + 2); STAGE(p, 0, 0, g + 2); }
        BARX(); MM(1, 1);
        if (g < NT - 2) { VMW(6); } else { VMW(0); }
        BARX();
    }

    if constexpr (BF16OUT) {
        bf16* lt = (bf16*)smem;                     // all LDS reads done (final barrier above)
#pragma unroll
        for (int RF = 0; RF < 8; RF++) {
            const int row = wm * 128 + (RF >> 2) * 64 + (RF & 3) * 16 + quad * 4;
#pragma unroll
            for (int CF = 0; CF < 4; CF++) {
                const int col = wn * 64 + (CF >> 1) * 32 + (CF & 1) * 16 + l16;
                float bv = BIAS ? bias[bn + col] : 0.f;
#pragma unroll
                for (int rr = 0; rr < 4; rr++) {
                    float v = acc[RF][CF][rr] + bv;
                    if constexpr (RELU) v = fmaxf(v, 0.f);
                    lt[(row + rr) * 280 + col] = f2b(v);
                }
            }
        }
        asm volatile("s_waitcnt lgkmcnt(0)" ::: "memory");
        BARX();
        bf16* C = (bf16*)Cv;
#pragma unroll
        for (int it = 0; it < 16; it++) {
            int c = it * 512 + tid;
            int rr = c >> 5, c8 = (c & 31) * 8;
            *(short8*)(C + (size_t)(bm + rr) * N + bn + c8) =
                *(const short8*)(lt + rr * 280 + c8);
        }
    } else {
        float* C = (float*)Cv;
#pragma unroll
        for (int RF = 0; RF < 8; RF++) {
            const int gr = bm + wm * 128 + (RF >> 2) * 64 + (RF & 3) * 16 + quad * 4;
#pragma unroll
            for (int CF = 0; CF < 4; CF++) {
                const int gc = bn + wn * 64 + (CF >> 1) * 32 + (CF & 1) * 16 + l16;
                float bv = BIAS ? bias[gc] : 0.f;
#pragma unroll
                for (int rr = 0; rr < 4; rr++) {
                    float v = acc[RF][CF][rr] + bv;
                    if constexpr (RES) v += res[(size_t)(gr + rr) * N + gc];
                    if constexpr (RELU) v = fmaxf(v, 0.f);
                    C[(size_t)(gr + rr) * N + gc] = v;
                }
            }
        }
    }
#undef STAGE
#undef BARX
#undef VMW
#undef LDA
#undef LDB
#undef MM
}

// ============== 256x192 4-phase GEMM (FF2), r5 schedule, bm-clustered XCD map =================
template <int NTC, int TPB, bool RELU, bool BIAS, bool RES, bool BF16OUT>
__global__ __launch_bounds__(512, 2) void gemm192_kernel(
    const bf16* __restrict__ A, const bf16* __restrict__ Bt,
    const float* __restrict__ bias, const float* __restrict__ res,
    void* __restrict__ Cv, int N)
{
    constexpr int KC = NTC * 64;
    constexpr int NG = NTC * TPB;
    extern __shared__ __align__(16) char smem[];

    // bm-clustered XCD map (grid = 256): XCD k8 serves bm in {8*k8..8*k8+7} x 4 bn-groups
    const int k8 = blockIdx.x & 7, q = blockIdx.x >> 3;
    const int sid = (q >> 3) * 64 + k8 * 8 + (q & 7);
    const int bm = (sid & 63) << 8;
    const int bnBase = (sid >> 6) * (TPB * 192);

    const int tid = threadIdx.x;
    const int w = tid >> 6, lane = tid & 63;
    const int wm = w >> 1, wn = w & 1;              // 4 x 2 wave grid
    const int l16 = lane & 15, quad = lane >> 4;

    const int rstg = (w >> 1) * 16 + (lane >> 2);
    const int cstg = (w & 1) * 32 + (((lane & 3) * 8) ^ ((lane & 32) ? 16 : 0));
    const bf16* aSrc = A + (size_t)(bm + rstg) * KC + cstg;
    const bf16* bSrc = Bt + (size_t)(bnBase + rstg) * KC + cstg;
    const int stgoff = w * 1024;                    // wave-uniform; HW adds lane*16

    const int xr = (quad * 16) ^ ((l16 & 8) ? 32 : 0);
    const int aoff = wm * 8192 + l16 * 64 + xr;             // + qm*4096 + fm*2048 + s*1024
    const int boff = 32768 + wn * 12288 + l16 * 64 + xr;    // + qn*6144 + fn*2048 + s*1024

#define STG2(BO, ISB, CH) gload_lds16( \
        ((ISB) ? bS2 : aS2) + (size_t)(CH) * 64 * KC, \
        smem + (BO) + (ISB) * 32768 + (CH) * 8192 + stgoff)

#define BARX() asm volatile("s_barrier" ::: "memory")
#define VMW(N_) asm volatile("s_waitcnt vmcnt(" #N_ ")" ::: "memory")
#define LGW0() asm volatile("s_waitcnt lgkmcnt(0)" ::: "memory")

    floatx4 acc[4][6] = {};
    short8 a[2][2][2], b[2][3][2];                  // a[qm][fm][s], b[qn][fn][s]

#define LDA(QM, CB) { _Pragma("unroll") for (int fm = 0; fm < 2; fm++) { \
    _Pragma("unroll") for (int s = 0; s < 2; s++) \
        a[QM][fm][s] = *(const short8*)((CB) + aoff + (QM) * 4096 + fm * 2048 + s * 1024); } }
#define LDB(QN, CB) { _Pragma("unroll") for (int fn = 0; fn < 3; fn++) { \
    _Pragma("unroll") for (int s = 0; s < 2; s++) \
        b[QN][fn][s] = *(const short8*)((CB) + boff + (QN) * 6144 + fn * 2048 + s * 1024); } }
#define MM(QM, QN) { __builtin_amdgcn_s_setprio(1); \
    _Pragma("unroll") for (int fm = 0; fm < 2; fm++) { \
    _Pragma("unroll") for (int fn = 0; fn < 3; fn++) { \
    _Pragma("unroll") for (int s = 0; s < 2; s++) \
        acc[(QM)*2+fm][(QN)*3+fn] = __builtin_amdgcn_mfma_f32_16x16x32_bf16( \
            a[QM][fm][s], b[(QN)][fn][s], acc[(QM)*2+fm][(QN)*3+fn], 0, 0, 0); } } \
    __builtin_amdgcn_s_setprio(0); }

    // prologue: all 7 chunks of vgroup0 -> buf0, then vgroup1 -> buf1 (both t=0; NTC>=2)
    {
        const bf16* aS2 = aSrc;           const bf16* bS2 = bSrc;
#pragma unroll
        for (int c = 0; c < 4; c++) STG2(0, 0, c);
#pragma unroll
        for (int c = 0; c < 3; c++) STG2(0, 1, c);
        aS2 = aSrc + 64; bS2 = bSrc + 64;
#pragma unroll
        for (int c = 0; c < 4; c++) STG2(57344, 0, c);
#pragma unroll
        for (int c = 0; c < 3; c++) STG2(57344, 1, c);
    }
    VMW(7);            // own vgroup0 chunks landed (vgroup1's 7 stay in flight)
    BARX();            // -> ALL waves' vgroup0 chunks landed
    LDA(0, smem); LDB(0, smem);     // pre-read G=0 ph0 operands (buf0)

    for (int G = 0; G < NG; ++G) {
        const int bo = (G & 1) * 57344;
        const char* cb = smem + bo;
        const char* nb = smem + (bo ^ 57344);
        const int v = G + 2;
        const bf16* aS2 = aSrc;
        const bf16* bS2 = bSrc;
        if (v < NG) {
            const int t2 = v / NTC, g2 = v - t2 * NTC;
            aS2 = aSrc + (size_t)g2 * 64;
            bS2 = bSrc + (size_t)t2 * (192 * (size_t)KC) + (size_t)g2 * 64;
        }
        // ---- ph0: MM(0,0) on pre-read a[0],b[0]; fetch A(qm1) ----
        LDA(1, cb);
        MM(0, 0);
        BARX();
        // ---- ph1: MM(1,0); fetch B(qn1); publish tile G+1 ----
        LDB(1, cb);
        MM(1, 0);
        VMW(0);
        BARX();
        // ---- ph2: stage A(G+2); pre-read B(qn0,G+1) from nb; MM(1,1) ----
        if (v < NG) { STG2(bo, 0, 0); STG2(bo, 0, 1); STG2(bo, 0, 2); STG2(bo, 0, 3); }
        if (G + 1 < NG) LDB(0, nb);
        MM(1, 1);
        BARX();
        // ---- ph3: stage B(G+2); MM(0,1); reload A(qm0,G+1) ----
        if (v < NG) { STG2(bo, 1, 0); STG2(bo, 1, 1); STG2(bo, 1, 2); }
        MM(0, 1);
        if (G + 1 < NG) LDA(0, nb);
        BARX();
    }

    if constexpr (!BF16OUT) {
        float* C = (float*)Cv;
        const int bn = bnBase;                      // TPB==1 for fp32-out path
#pragma unroll
        for (int mf = 0; mf < 4; mf++) {
            const int gr = bm + wm * 64 + mf * 16 + quad * 4;
#pragma unroll
            for (int nf = 0; nf < 6; nf++) {
                const int gc = bn + wn * 96 + nf * 16 + l16;
                float bv = BIAS ? bias[gc] : 0.f;
#pragma unroll
                for (int r = 0; r < 4; r++) {
                    float v = acc[mf][nf][r] + bv;
                    if constexpr (RES) v += res[(size_t)(gr + r) * N + gc];
                    if constexpr (RELU) v = fmaxf(v, 0.f);
                    C[(size_t)(gr + r) * N + gc] = v;
                }
            }
        }
    }
#undef STG2
#undef BARX
#undef VMW
#undef LGW0
#undef LDA
#undef LDB
#undef MM
}

// ---------------- causal attention, online softmax; qkv layout [BT][216]: q|k|v each 72 cols ----------------
__global__ __launch_bounds__(256) void attn_kernel(const bf16* __restrict__ qkv, bf16* __restrict__ o_pad)
{
    int blk = blockIdx.x;
    int half = blk & 1;
    int bh = blk >> 1;
    int b = bh / NH, h = bh % NH;
    int wave = threadIdx.x >> 6, lane = threadIdx.x & 63;
    const int jmap0[4] = {0, 2, 5, 7}, jmap1[4] = {1, 3, 4, 6};
    int j = half ? jmap1[wave] : jmap0[wave];
    int t = j * 64 + lane;
    int smax = half ? 448 : 512;

    __shared__ float ks[512 * 6];
    __shared__ float vs[512 * 6];
    const bf16* base = qkv + (size_t)b * 512 * 216;
    for (int i = threadIdx.x; i < smax * 6; i += 256) {
        int s = i / 6, e = i % 6;
        ks[i] = b2f(base[s * 216 + 72 + h * 6 + e]);
        vs[i] = b2f(base[s * 216 + 144 + h * 6 + e]);
    }
    __syncthreads();

    float q0 = b2f(base[t * 216 + h * 6 + 0]);
    float q1 = b2f(base[t * 216 + h * 6 + 1]);
    float q2 = b2f(base[t * 216 + h * 6 + 2]);
    float q3 = b2f(base[t * 216 + h * 6 + 3]);
    float q4 = b2f(base[t * 216 + h * 6 + 4]);
    float q5 = b2f(base[t * 216 + h * 6 + 5]);

    const float scale = 0.4082482904638630f;  // 1/sqrt(6)
    float m = -1e30f, l = 0.f;
    float o0 = 0, o1 = 0, o2 = 0, o3 = 0, o4 = 0, o5 = 0;
    for (int s = 0; s <= t; s++) {
        const float* kk = &ks[s * 6];
        float sc = (q0 * kk[0] + q1 * kk[1] + q2 * kk[2] + q3 * kk[3] + q4 * kk[4] + q5 * kk[5]) * scale;
        float nm = fmaxf(m, sc);
        float alpha = __expf(m - nm);
        float p = __expf(sc - nm);
        l = l * alpha + p;
        const float* vv = &vs[s * 6];
        o0 = o0 * alpha + p * vv[0];
        o1 = o1 * alpha + p * vv[1];
        o2 = o2 * alpha + p * vv[2];
        o3 = o3 * alpha + p * vv[3];
        o4 = o4 * alpha + p * vv[4];
        o5 = o5 * alpha + p * vv[5];
        m = nm;
    }
    float inv = 1.f / l;
    bf16* orow = o_pad + (size_t)(b * 512 + t) * 96 + h * 6;
    orow[0] = f2b(o0 * inv);
    orow[1] = f2b(o1 * inv);
    orow[2] = f2b(o2 * inv);
    orow[3] = f2b(o3 * inv);
    orow[4] = f2b(o4 * inv);
    orow[5] = f2b(o5 * inv);
    // cols 72..95 of o_pad stay poison (finite bf16): matching wo_t k-cols are zero -> contributes 0.
}

extern "C" void kernel_launch(void* const* d_in, const int* in_sizes, int n_in,
                              void* d_out, int out_size, void* d_ws, size_t ws_size,
                              hipStream_t stream)
{
    const float* x   = (const float*)d_in[0];
    const float* Wq  = (const float*)d_in[1];
    const float* Wk  = (const float*)d_in[2];
    const float* Wv  = (const float*)d_in[3];
    const float* Wo  = (const float*)d_in[4];
    const float* bo  = (const float*)d_in[5];
    const float* W1  = (const float*)d_in[6];
    const float* b1  = (const float*)d_in[7];
    const float* W2  = (const float*)d_in[8];
    const float* b2  = (const float*)d_in[9];
    const float* g1  = (const float*)d_in[10];
    const float* be1 = (const float*)d_in[11];
    const float* g2  = (const float*)d_in[12];
    const float* be2 = (const float*)d_in[13];

    char* ws = (char*)d_ws;
    size_t off = 0;
    auto alloc = [&](size_t bytes) {
        void* p = ws + off;
        off = (off + bytes + 255) & ~(size_t)255;
        return p;
    };
    bf16*  xn    = (bf16*)alloc((size_t)BT * DIM * 2);   // LN output (reused for both LNs)
    bf16*  qkvb  = (bf16*)alloc((size_t)BT * 216 * 2);
    bf16*  o_pad = (bf16*)alloc((size_t)BT * 96 * 2);
    float* x1    = (float*)alloc((size_t)BT * DIM * 4);  // residual stream after attention, fp32
    bf16*  ffb   = (bf16*)alloc((size_t)BT * DFF * 2);
    bf16*  wqkv  = (bf16*)alloc((size_t)256 * 768 * 2);  // padded to 256 rows (zeros)
    bf16*  wo_t  = (bf16*)alloc((size_t)768 * 96 * 2);
    bf16*  w1t   = (bf16*)alloc((size_t)3072 * 768 * 2);
    bf16*  w2t   = (bf16*)alloc((size_t)768 * 3072 * 2);

    // allow >64KB dynamic LDS (host-side, graph-capture safe)
    hipFuncSetAttribute(reinterpret_cast<const void*>(&gemm256_kernel<true, true, false, true>),
                        hipFuncAttributeMaxDynamicSharedMemorySize, 256 * 280 * 2);
    hipFuncSetAttribute(reinterpret_cast<const void*>(&gemm192_kernel<48, 1, false, true, true, false>),
                        hipFuncAttributeMaxDynamicSharedMemorySize, 114688);

    const int PACK_N = 256 * 768 + 768 * 96;
    pack_small_kernel<<<(PACK_N + 255) / 256, 256, 0, stream>>>(Wq, Wk, Wv, Wo, wqkv, wo_t);
    transpose_kernel<<<dim3(3072 / 32, 768 / 32), 256, 0, stream>>>(W1, w1t, 768, 3072);
    transpose_kernel<<<dim3(768 / 32, 3072 / 32), 256, 0, stream>>>(W2, w2t, 3072, 768);

    ln_kernel<<<BT, 192, 0, stream>>>(x, g1, be1, xn);
    gemm_kernel<2, false, false, false, true><<<dim3(128, 2), 256, 0, stream>>>(
        xn, wqkv, nullptr, nullptr, qkvb, BT, 216, 768);
    attn_kernel<<<32 * NH * 2, 256, 0, stream>>>(qkvb, o_pad);
    gemm_kernel<1, false, true, true, false><<<dim3(128, 6), 256, 0, stream>>>(
        o_pad, wo_t, bo, x, x1, BT, 768, 96);
    ln_kernel<<<BT, 192, 0, stream>>>(x1, g2, be2, xn);
    // FF1: [16384x768] @ [768x3072] -> bf16 (+bias, relu): 256^2 8-phase, grid 768, bm-clustered
    gemm256_kernel<true, true, false, true><<<768, 512, 256 * 280 * 2, stream>>>(
        xn, w1t, b1, nullptr, ffb, BT, 3072, 768);
    // FF2: [16384x3072] @ [3072x768] -> fp32 (+bias, +res): gemm192, grid 256, bm-clustered
    gemm192_kernel<48, 1, false, true, true, false><<<256, 512, 114688, stream>>>(
        ffb, w2t, b2, x1, (float*)d_out, 768);
}